// Round 1
// baseline (303.294 us; speedup 1.0000x reference)
//
#include <hip/hip_runtime.h>
#include <hip/hip_bf16.h>
#include <stdint.h>

// Problem constants (reference: B=4, S=2048, D_IN=D_K=D_V=1024)
#define B_ 4
#define S_ 2048
#define D_ 1024

typedef __attribute__((ext_vector_type(8))) short short8;   // 8 bf16 = 4 VGPRs
typedef __attribute__((ext_vector_type(4))) float floatx4;  // MFMA C/D

__device__ __forceinline__ unsigned short bf16_rne(float f) {
  union { float f; uint32_t u; } c; c.f = f;
  uint32_t u = c.u;
  return (unsigned short)((u + 0x7fffu + ((u >> 16) & 1u)) >> 16);
}

__device__ __forceinline__ void gl2lds16(const void* g, void* l) {
  // async global->LDS, 16B per lane; LDS dest is wave-uniform base + lane*16
  __builtin_amdgcn_global_load_lds(
      (const __attribute__((address_space(1))) void*)g,
      (__attribute__((address_space(3))) void*)l, 16, 0, 0);
}

// ---- merged prep: casts of query/key/Wq/Wk, bias packing, value transpose ----
__global__ __launch_bounds__(256) void prep_all(
    const float* __restrict__ q, const float* __restrict__ k,
    const float* __restrict__ wq, const float* __restrict__ wk,
    const float* __restrict__ bq, const float* __restrict__ bk,
    const float* __restrict__ v,
    unsigned short* __restrict__ oq, unsigned short* __restrict__ ok,
    unsigned short* __restrict__ owq, unsigned short* __restrict__ owk,
    float* __restrict__ bias, unsigned short* __restrict__ vt) {
  __shared__ float tile[32][33];
  const int blk = blockIdx.x;
  if (blk < 18432) {
    int i = blk * 256 + threadIdx.x;
    const float* src; unsigned short* dst; int off;
    if (i < 2097152)      { src = q;  dst = oq;  off = i; }
    else if (i < 4194304) { src = k;  dst = ok;  off = i - 2097152; }
    else if (i < 4456448) { src = wq; dst = owq; off = i - 4194304; }
    else                  { src = wk; dst = owk; off = i - 4456448; }
    float4 vv = ((const float4*)src)[off];
    uint32_t p0 = (uint32_t)bf16_rne(vv.x) | ((uint32_t)bf16_rne(vv.y) << 16);
    uint32_t p1 = (uint32_t)bf16_rne(vv.z) | ((uint32_t)bf16_rne(vv.w) << 16);
    ((uint2*)dst)[off] = make_uint2(p0, p1);
  } else if (blk < 18434) {
    int j = (blk - 18432) * 256 + threadIdx.x;  // 0..511
    const float* src = (j < 256) ? bq : bk;
    ((float4*)bias)[j] = ((const float4*)src)[j & 255];
  } else {
    const int bi = blk - 18434;
    const int d0 = (bi & 31) * 32;          // D/32 = 32
    const int s0 = ((bi >> 5) & 63) * 32;   // S/32 = 64
    const int b  = bi >> 11;                // B = 4
    const int tx = threadIdx.x & 31, ty = threadIdx.x >> 5;  // (32,8)
    const float* src = v + (size_t)b * S_ * D_;
#pragma unroll
    for (int i = 0; i < 4; ++i)
      tile[ty + i * 8][tx] = src[(size_t)(s0 + ty + i * 8) * D_ + d0 + tx];
    __syncthreads();
    unsigned short* dst = vt + (size_t)b * D_ * S_;
#pragma unroll
    for (int i = 0; i < 4; ++i)
      dst[(size_t)(d0 + ty + i * 8) * S_ + s0 + tx] = bf16_rne(tile[tx][ty + i * 8]);
  }
}

// ---------------- legacy BT-GEMM (kept for the AV step: BM=128, 512 blocks) ----------------
template <int EPI, int BM>
__global__ __launch_bounds__(256, BM == 128 ? 3 : 2) void gemm_bt(
    const unsigned short* __restrict__ A, const unsigned short* __restrict__ Bm,
    void* __restrict__ Cv, const float* __restrict__ bias,
    int N, int K, float scale,
    long long sA, long long sB, long long sC, long long sBias) {
  constexpr int IC = BM / 32;    // A-frags per wave (m direction)
  constexpr int AST = BM / 64;   // A staging instrs per thread per k32
  __shared__ unsigned short smA[2][BM * 32];
  __shared__ unsigned short smB[2][128 * 32];

  const int gx = gridDim.x, gy = gridDim.y;
  const int lin = blockIdx.x + gx * (blockIdx.y + gy * blockIdx.z);
  const int total = gx * gy * gridDim.z;
  const int g = (lin & 7) * (total >> 3) + (lin >> 3);
  const int z = g / (gx * gy);
  const int rem = g - z * (gx * gy);
  const int by = rem / gx;
  const int bx = rem - by * gx;

  const unsigned short* Ab = A + (size_t)z * sA;
  const unsigned short* Bb = Bm + (size_t)z * sB;

  const int tile_n = bx * 128;
  const int tile_m = by * BM;

  const int t = threadIdx.x;
  const int w = t >> 6;        // wave 0..3
  const int l = t & 63;        // lane
  const int wr = w >> 1, wc = w & 1;  // 2x2 wave grid

  floatx4 acc[IC][4];
#pragma unroll
  for (int i = 0; i < IC; ++i)
#pragma unroll
    for (int j = 0; j < 4; ++j) acc[i][j] = (floatx4){0.f, 0.f, 0.f, 0.f};

  const int srow = l >> 2;                                  // staged quarter-row
  const int scb  = ((l & 3) ^ ((l >> 3) & 3)) * 16;         // swizzled global chunk (bytes)
  const int rm   = l & 15;                                  // fragment row within 16
  const int kcsw = ((l >> 4) ^ ((rm >> 1) & 3)) * 16;       // swizzled LDS chunk (bytes)

  for (int kt = 0; kt < K; kt += 64) {
#pragma unroll
    for (int h = 0; h < 2; ++h) {
#pragma unroll
      for (int i = 0; i < AST; ++i) {
        const int r = (i * 4 + w) * 16 + srow;
        gl2lds16((const char*)Ab + (size_t)(tile_m + r) * K * 2 + (kt + h * 32) * 2 + scb,
                 (char*)smA[h] + (i * 4 + w) * 1024);
      }
#pragma unroll
      for (int i = 0; i < 2; ++i) {
        const int r = (i * 4 + w) * 16 + srow;
        gl2lds16((const char*)Bb + (size_t)(tile_n + r) * K * 2 + (kt + h * 32) * 2 + scb,
                 (char*)smB[h] + (i * 4 + w) * 1024);
      }
    }
    __syncthreads();  // drains vmcnt -> both staged tiles visible

#pragma unroll
    for (int h = 0; h < 2; ++h) {
      short8 bfr[4];
#pragma unroll
      for (int j = 0; j < 4; ++j)
        bfr[j] = *(const short8*)((const char*)smB[h] + (wc * 64 + j * 16 + rm) * 64 + kcsw);
#pragma unroll
      for (int i = 0; i < IC; ++i) {
        const short8 af = *(const short8*)((const char*)smA[h] +
                                           (wr * (BM / 2) + i * 16 + rm) * 64 + kcsw);
#pragma unroll
        for (int j = 0; j < 4; ++j)
          acc[i][j] = __builtin_amdgcn_mfma_f32_16x16x32_bf16(af, bfr[j], acc[i][j], 0, 0, 0);
      }
    }
    __syncthreads();  // protect LDS before next stage
  }

#pragma unroll
  for (int i = 0; i < IC; ++i) {
#pragma unroll
    for (int j = 0; j < 4; ++j) {
      const int n = tile_n + wc * 64 + j * 16 + rm;
      const int m0 = tile_m + wr * (BM / 2) + i * 16 + (l >> 4) * 4;
      if (EPI == 0) {
        const float bv = bias[(size_t)z * sBias + n];
        unsigned short* C = (unsigned short*)Cv + (size_t)z * sC;
#pragma unroll
        for (int r = 0; r < 4; ++r)
          C[(size_t)(m0 + r) * N + n] = bf16_rne(acc[i][j][r] + bv);
      } else if (EPI == 1) {
        float* C = (float*)Cv + (size_t)z * sC;
#pragma unroll
        for (int r = 0; r < 4; ++r)
          C[(size_t)(m0 + r) * N + n] = acc[i][j][r] * scale;
      } else {
        unsigned short* C = (unsigned short*)Cv + (size_t)z * sC;
#pragma unroll
        for (int r = 0; r < 4; ++r)
          C[(size_t)(m0 + r) * N + n] = bf16_rne(acc[i][j][r] * scale);
      }
    }
  }
}

// ================= 8-phase 256x256 BT-GEMM (T2+T3+T4+T5), BK=64, 8 waves =================
// C[m,n] = sum_k A[m,k]*B[n,k]. 512 threads = 8 waves (2M x 4N), wave tile 128x64.
// LDS 128 KiB: smA/smB[2][256x64] bf16, linear layout (global_load_lds direct).
// Chunk swizzle: LDS 16B-chunk c of row r holds global chunk c ^ ((r&15)>>1)
// (involution; applied on the gl2lds SOURCE and on the ds_read address).
// Phase order per K-tile t (buf cur=t&1):
//  P1: ds_read A-mh0(8) B-nh0(4); stage Ah1(t+1)->nxt; BAR; 16 MFMA (mh0,nh0); BAR
//  P2: ds_read B-nh1(4);                               BAR; 16 MFMA (mh0,nh1); BAR
//  P3: ds_read A-mh1(8); stage Bh0(t+2)->cur;          BAR; 16 MFMA (mh1,nh1); BAR
//  P4: stage Bh1(t+2)+Ah0(t+2)->cur; 16 MFMA (mh1,nh0); s_waitcnt vmcnt(6); BAR
// Legality: all B-reads of cur end at P2's barrier, all A-reads at P3's barrier,
// so P3/P4 may stage tile t+2 into cur. vmcnt(6) leaves exactly the 3 youngest
// half-tiles (all for t+2) in flight while guaranteeing tile t+1 fully landed.
#define BAR8() { asm volatile("" ::: "memory"); __builtin_amdgcn_s_barrier(); \
                 asm volatile("" ::: "memory"); }

#define LOAD_A8(mh)                                                            \
  _Pragma("unroll") for (int f = 0; f < 4; ++f) {                              \
    const char* p_ = (const char*)sa + ((wr * 128 + (mh) * 64 + f * 16) * 128);\
    a[f][0] = *(const short8*)(p_ + aoff0);                                    \
    a[f][1] = *(const short8*)(p_ + aoff1);                                    \
  }

#define LOAD_B8(nh, barr)                                                      \
  _Pragma("unroll") for (int j = 0; j < 2; ++j) {                              \
    const char* p_ = (const char*)sb + ((wc * 64 + (nh) * 32 + j * 16) * 128); \
    barr[j][0] = *(const short8*)(p_ + aoff0);                                 \
    barr[j][1] = *(const short8*)(p_ + aoff1);                                 \
  }

#define QUAD8(mh, nh, barr)                                                    \
  _Pragma("unroll") for (int f = 0; f < 4; ++f)                                \
  _Pragma("unroll") for (int j = 0; j < 2; ++j)                                \
  _Pragma("unroll") for (int kk = 0; kk < 2; ++kk)                             \
    acc[(mh) * 4 + f][(nh) * 2 + j] =                                          \
        __builtin_amdgcn_mfma_f32_16x16x32_bf16(                               \
            a[f][kk], barr[j][kk], acc[(mh) * 4 + f][(nh) * 2 + j], 0, 0, 0);

#define STAGE8(mat, row0, kt, ldsb)                                            \
  _Pragma("unroll") for (int r = 0; r < 2; ++r)                                \
    gl2lds16((const char*)(mat) +                                              \
                 ((size_t)((row0) + r * 64 + stg_row) * K + (kt)) * 2 + stg_cb,\
             (char*)(ldsb) + r * 8192 + w * 1024);

#define STAGE8_A(buf, half, kt) \
  STAGE8(Ab, tile_m + (half) * 128, kt, (char*)smA[buf] + (half) * 16384)
#define STAGE8_B(buf, half, kt) \
  STAGE8(Bb, tile_n + (half) * 128, kt, (char*)smB[buf] + (half) * 16384)

template <int EPI>
__global__ __launch_bounds__(512, 2) void gemm8_bt(
    const unsigned short* __restrict__ A, const unsigned short* __restrict__ Bm,
    void* __restrict__ Cv, const float* __restrict__ bias,
    int N, int K, float scale,
    long long sA, long long sB, long long sC, long long sBias) {
  __shared__ unsigned short smA[2][256 * 64];
  __shared__ unsigned short smB[2][256 * 64];

  // XCD-aware remap (grid total = 256, divisible by 8)
  const int gx = gridDim.x, gy = gridDim.y;
  const int lin = blockIdx.x + gx * (blockIdx.y + gy * blockIdx.z);
  const int total = gx * gy * gridDim.z;
  const int g = (lin & 7) * (total >> 3) + (lin >> 3);
  const int z = g / (gx * gy);
  const int rem = g - z * (gx * gy);
  const int by = rem / gx;
  const int bx = rem - by * gx;

  const unsigned short* Ab = A + (size_t)z * sA;
  const unsigned short* Bb = Bm + (size_t)z * sB;
  const int tile_n = bx * 256;
  const int tile_m = by * 256;

  const int tid = threadIdx.x;
  const int w = tid >> 6, l = tid & 63;
  const int wr = w >> 2, wc = w & 3;      // 2x4 wave grid

  // staging constants: thread covers LDS row (r*64 + stg_row), chunk l&7
  const int stg_row = w * 8 + (l >> 3);               // 0..63 (+ r*64)
  const int stg_cb  = (((l & 7) ^ ((stg_row & 15) >> 1)) << 4);

  // fragment-read constants
  const int rm = l & 15, kc = l >> 4;
  const int q8 = (rm >> 1) & 7;
  const int aoff0 = rm * 128 + ((kc ^ q8) << 4);
  const int aoff1 = aoff0 ^ 64;                       // k-half 1 (chunk bit2)

  const int NT = K >> 6;

  floatx4 acc[8][4];
#pragma unroll
  for (int i = 0; i < 8; ++i)
#pragma unroll
    for (int j = 0; j < 4; ++j) acc[i][j] = (floatx4){0.f, 0.f, 0.f, 0.f};

  short8 a[4][2], b0[2][2], b1[2][2];

  // ---- prologue: tile0 (4 halves) + Bh0/Bh1/Ah0 of tile1; vmcnt(6) => tile0 landed
  {
    const int k1 = (NT > 1 ? 64 : 0);
    STAGE8_A(0, 0, 0);
    STAGE8_A(0, 1, 0);
    STAGE8_B(0, 0, 0);
    STAGE8_B(0, 1, 0);
    STAGE8_B(1, 0, k1);
    STAGE8_B(1, 1, k1);
    STAGE8_A(1, 0, k1);
  }
  asm volatile("s_waitcnt vmcnt(6)" ::: "memory");
  __builtin_amdgcn_s_barrier();
  asm volatile("" ::: "memory");

  for (int tt = 0; tt < NT; ++tt) {
    const int cur = tt & 1, nxt = cur ^ 1;
    const unsigned short* sa = smA[cur];
    const unsigned short* sb = smB[cur];
    const int ktn  = ((tt + 1 < NT) ? tt + 1 : NT - 1) * 64;  // tile t+1 (clamped)
    const int ktn2 = ((tt + 2 < NT) ? tt + 2 : NT - 1) * 64;  // tile t+2 (clamped)

    // ---- P1
    LOAD_A8(0)
    LOAD_B8(0, b0)
    STAGE8_A(nxt, 1, ktn)
    BAR8()
    __builtin_amdgcn_s_setprio(1);
    QUAD8(0, 0, b0)
    __builtin_amdgcn_s_setprio(0);
    BAR8()

    // ---- P2
    LOAD_B8(1, b1)
    BAR8()
    __builtin_amdgcn_s_setprio(1);
    QUAD8(0, 1, b1)
    __builtin_amdgcn_s_setprio(0);
    BAR8()

    // ---- P3
    LOAD_A8(1)
    STAGE8_B(cur, 0, ktn2)
    BAR8()
    __builtin_amdgcn_s_setprio(1);
    QUAD8(1, 1, b1)
    __builtin_amdgcn_s_setprio(0);
    BAR8()

    // ---- P4 (no LDS reads; b0 kept live from P1)
    STAGE8_B(cur, 1, ktn2)
    STAGE8_A(cur, 0, ktn2)
    __builtin_amdgcn_s_setprio(1);
    QUAD8(1, 0, b0)
    __builtin_amdgcn_s_setprio(0);
    asm volatile("s_waitcnt vmcnt(6)" ::: "memory");
    __builtin_amdgcn_s_barrier();
    asm volatile("" ::: "memory");
  }

  // Epilogue. C/D layout: col = lane&15, row = (lane>>4)*4 + reg
#pragma unroll
  for (int jg = 0; jg < 4; ++jg) {
    const int n = tile_n + wc * 64 + jg * 16 + rm;
    float bv = 0.f;
    if (EPI == 0) bv = bias[(size_t)z * sBias + n];
#pragma unroll
    for (int fg = 0; fg < 8; ++fg) {
      const int m0 = tile_m + wr * 128 + fg * 16 + (l >> 4) * 4;
      if (EPI == 0) {
        unsigned short* C = (unsigned short*)Cv + (size_t)z * sC;
#pragma unroll
        for (int r = 0; r < 4; ++r)
          C[(size_t)(m0 + r) * N + n] = bf16_rne(acc[fg][jg][r] + bv);
      } else if (EPI == 1) {
        float* C = (float*)Cv + (size_t)z * sC;
#pragma unroll
        for (int r = 0; r < 4; ++r)
          C[(size_t)(m0 + r) * N + n] = acc[fg][jg][r] * scale;
      } else {
        unsigned short* C = (unsigned short*)Cv + (size_t)z * sC;
#pragma unroll
        for (int r = 0; r < 4; ++r)
          C[(size_t)(m0 + r) * N + n] = bf16_rne(acc[fg][jg][r] * scale);
      }
    }
  }
}

// ---------------- row softmax: bf16 logits [rows,2048] -> bf16 attn ----------------
__global__ __launch_bounds__(256) void softmax_bf16(
    const unsigned short* __restrict__ logits, unsigned short* __restrict__ attn) {
  const int row = blockIdx.x;
  const int t = threadIdx.x;
  uint4 raw = *(const uint4*)(logits + (size_t)row * S_ + t * 8);
  float x[8];
  const uint32_t ru[4] = {raw.x, raw.y, raw.z, raw.w};
#pragma unroll
  for (int i = 0; i < 4; ++i) {
    union { uint32_t u; float f; } lo, hi;
    lo.u = ru[i] << 16;
    hi.u = ru[i] & 0xffff0000u;
    x[2 * i] = lo.f;
    x[2 * i + 1] = hi.f;
  }
  float m = x[0];
#pragma unroll
  for (int i = 1; i < 8; ++i) m = fmaxf(m, x[i]);
#pragma unroll
  for (int off = 32; off > 0; off >>= 1) m = fmaxf(m, __shfl_xor(m, off));
  __shared__ float sm4[4], ss4[4];
  const int wv = t >> 6, ln = t & 63;
  if (ln == 0) sm4[wv] = m;
  __syncthreads();
  m = fmaxf(fmaxf(sm4[0], sm4[1]), fmaxf(sm4[2], sm4[3]));
  float s = 0.f;
  const float LOG2E = 1.44269504088896340736f;
#pragma unroll
  for (int i = 0; i < 8; ++i) {
    x[i] = exp2f((x[i] - m) * LOG2E);
    s += x[i];
  }
#pragma unroll
  for (int off = 32; off > 0; off >>= 1) s += __shfl_xor(s, off);
  if (ln == 0) ss4[wv] = s;
  __syncthreads();
  s = ss4[0] + ss4[1] + ss4[2] + ss4[3];
  const float inv = 1.0f / s;
  uint32_t p[4];
#pragma unroll
  for (int i = 0; i < 4; ++i)
    p[i] = (uint32_t)bf16_rne(x[2 * i] * inv) |
           ((uint32_t)bf16_rne(x[2 * i + 1] * inv) << 16);
  *(uint4*)(attn + (size_t)row * S_ + t * 8) = make_uint4(p[0], p[1], p[2], p[3]);
}

extern "C" void kernel_launch(void* const* d_in, const int* in_sizes, int n_in,
                              void* d_out, int out_size, void* d_ws, size_t ws_size,
                              hipStream_t stream) {
  (void)in_sizes; (void)n_in; (void)out_size; (void)ws_size;
  const float* query  = (const float*)d_in[0];
  const float* key_in = (const float*)d_in[1];
  const float* value  = (const float*)d_in[2];
  const float* Wq     = (const float*)d_in[3];
  const float* bq     = (const float*)d_in[4];
  const float* Wk     = (const float*)d_in[5];
  const float* bk     = (const float*)d_in[6];
  // d_in[7]=Wv, d_in[8]=bv: unused by the reference math (original model quirk).
  float* out = (float*)d_out;

  // Workspace layout (149 MiB used; every byte written before read each call)
  char* ws = (char*)d_ws;
  const size_t MiB = 1024 * 1024;
  unsigned short* Xq  = (unsigned short*)(ws);              // 16 MiB  query bf16
  unsigned short* Xk  = (unsigned short*)(ws + 16 * MiB);   // 16 MiB  key_in bf16 (contiguous after Xq)
  unsigned short* Wqb = (unsigned short*)(ws + 32 * MiB);   //  2 MiB  Wq bf16
  unsigned short* Wkb = (unsigned short*)(ws + 34 * MiB);   //  2 MiB  Wk bf16 (contiguous after Wqb)
  float*          Bias= (float*)(ws + 36 * MiB);            //  8 KiB  [bq | bk] packed
  unsigned short* Vt  = (unsigned short*)(ws + 37 * MiB);   // 16 MiB  value^T bf16 [B,D,S]
  unsigned short* Qp  = (unsigned short*)(ws + 53 * MiB);   // 16 MiB  Q bf16
  unsigned short* Kp  = (unsigned short*)(ws + 69 * MiB);   // 16 MiB  K bf16 (contiguous after Qp)
  unsigned short* Lg  = (unsigned short*)(ws + 85 * MiB);   // 32 MiB  logits bf16
  unsigned short* At  = (unsigned short*)(ws + 117 * MiB);  // 32 MiB  attn bf16

  // 1) all casts + bias pack + value transpose in one dispatch
  prep_all<<<26626, 256, 0, stream>>>(query, key_in, Wq, Wk, bq, bk, value,
                                      Xq, Xk, Wqb, Wkb, Bias, Vt);

  // 2) Q & K projections fused via z (8-phase 256^2: grid 4x32x2 = 256 = 1/CU)
  gemm8_bt<0><<<dim3(D_ / 256, B_ * S_ / 256, 2), 512, 0, stream>>>(
      Xq, Wqb, Qp, Bias, D_, D_, 0.f,
      (long long)B_ * S_ * D_, (long long)D_ * D_, (long long)B_ * S_ * D_, D_);

  // 3) logits = Q@K^T * D^-0.5 per batch -> bf16 (8-phase: grid 8x8x4 = 256)
  gemm8_bt<2><<<dim3(S_ / 256, S_ / 256, B_), 512, 0, stream>>>(
      Qp, Kp, Lg, nullptr, S_, D_, 0.03125f,
      (long long)S_ * D_, (long long)S_ * D_, (long long)S_ * S_, 0);

  // 4) attn = softmax(logits) rowwise -> bf16
  softmax_bf16<<<B_ * S_, 256, 0, stream>>>(Lg, At);

  // 5) out = attn @ value == BT-GEMM vs Vt (legacy BM=128: grid 8x16x4 = 512)
  gemm_bt<1, 128><<<dim3(D_ / 128, S_ / 128, B_), 256, 0, stream>>>(
      At, Vt, out, nullptr, D_, S_, 1.0f,
      (long long)S_ * S_, (long long)D_ * S_, (long long)S_ * D_, 0);
}

// Round 2
// 284.866 us; speedup vs baseline: 1.0647x; 1.0647x over previous
//
#include <hip/hip_runtime.h>
#include <hip/hip_bf16.h>
#include <stdint.h>

// Problem constants (reference: B=4, S=2048, D_IN=D_K=D_V=1024)
#define B_ 4
#define S_ 2048
#define D_ 1024

typedef __attribute__((ext_vector_type(8))) short short8;   // 8 bf16 = 4 VGPRs
typedef __attribute__((ext_vector_type(4))) float floatx4;  // MFMA C/D

__device__ __forceinline__ unsigned short bf16_rne(float f) {
  union { float f; uint32_t u; } c; c.f = f;
  uint32_t u = c.u;
  return (unsigned short)((u + 0x7fffu + ((u >> 16) & 1u)) >> 16);
}

__device__ __forceinline__ void gl2lds16(const void* g, void* l) {
  // async global->LDS, 16B per lane; LDS dest is wave-uniform base + lane*16
  __builtin_amdgcn_global_load_lds(
      (const __attribute__((address_space(1))) void*)g,
      (__attribute__((address_space(3))) void*)l, 16, 0, 0);
}

// ---- merged prep: casts of query/key/Wq/Wk, bias packing, value transpose ----
__global__ __launch_bounds__(256) void prep_all(
    const float* __restrict__ q, const float* __restrict__ k,
    const float* __restrict__ wq, const float* __restrict__ wk,
    const float* __restrict__ bq, const float* __restrict__ bk,
    const float* __restrict__ v,
    unsigned short* __restrict__ oq, unsigned short* __restrict__ ok,
    unsigned short* __restrict__ owq, unsigned short* __restrict__ owk,
    float* __restrict__ bias, unsigned short* __restrict__ vt) {
  __shared__ float tile[32][33];
  const int blk = blockIdx.x;
  if (blk < 18432) {
    int i = blk * 256 + threadIdx.x;
    const float* src; unsigned short* dst; int off;
    if (i < 2097152)      { src = q;  dst = oq;  off = i; }
    else if (i < 4194304) { src = k;  dst = ok;  off = i - 2097152; }
    else if (i < 4456448) { src = wq; dst = owq; off = i - 4194304; }
    else                  { src = wk; dst = owk; off = i - 4456448; }
    float4 vv = ((const float4*)src)[off];
    uint32_t p0 = (uint32_t)bf16_rne(vv.x) | ((uint32_t)bf16_rne(vv.y) << 16);
    uint32_t p1 = (uint32_t)bf16_rne(vv.z) | ((uint32_t)bf16_rne(vv.w) << 16);
    ((uint2*)dst)[off] = make_uint2(p0, p1);
  } else if (blk < 18434) {
    int j = (blk - 18432) * 256 + threadIdx.x;  // 0..511
    const float* src = (j < 256) ? bq : bk;
    ((float4*)bias)[j] = ((const float4*)src)[j & 255];
  } else {
    const int bi = blk - 18434;
    const int d0 = (bi & 31) * 32;          // D/32 = 32
    const int s0 = ((bi >> 5) & 63) * 32;   // S/32 = 64
    const int b  = bi >> 11;                // B = 4
    const int tx = threadIdx.x & 31, ty = threadIdx.x >> 5;  // (32,8)
    const float* src = v + (size_t)b * S_ * D_;
#pragma unroll
    for (int i = 0; i < 4; ++i)
      tile[ty + i * 8][tx] = src[(size_t)(s0 + ty + i * 8) * D_ + d0 + tx];
    __syncthreads();
    unsigned short* dst = vt + (size_t)b * D_ * S_;
#pragma unroll
    for (int i = 0; i < 4; ++i)
      dst[(size_t)(d0 + ty + i * 8) * S_ + s0 + tx] = bf16_rne(tile[tx][ty + i * 8]);
  }
}

// ---------------- legacy BT-GEMM (kept for the AV step: BM=128, 512 blocks) ----------------
template <int EPI, int BM>
__global__ __launch_bounds__(256, BM == 128 ? 3 : 2) void gemm_bt(
    const unsigned short* __restrict__ A, const unsigned short* __restrict__ Bm,
    void* __restrict__ Cv, const float* __restrict__ bias,
    int N, int K, float scale,
    long long sA, long long sB, long long sC, long long sBias) {
  constexpr int IC = BM / 32;    // A-frags per wave (m direction)
  constexpr int AST = BM / 64;   // A staging instrs per thread per k32
  __shared__ unsigned short smA[2][BM * 32];
  __shared__ unsigned short smB[2][128 * 32];

  const int gx = gridDim.x, gy = gridDim.y;
  const int lin = blockIdx.x + gx * (blockIdx.y + gy * blockIdx.z);
  const int total = gx * gy * gridDim.z;
  const int g = (lin & 7) * (total >> 3) + (lin >> 3);
  const int z = g / (gx * gy);
  const int rem = g - z * (gx * gy);
  const int by = rem / gx;
  const int bx = rem - by * gx;

  const unsigned short* Ab = A + (size_t)z * sA;
  const unsigned short* Bb = Bm + (size_t)z * sB;

  const int tile_n = bx * 128;
  const int tile_m = by * BM;

  const int t = threadIdx.x;
  const int w = t >> 6;        // wave 0..3
  const int l = t & 63;        // lane
  const int wr = w >> 1, wc = w & 1;  // 2x2 wave grid

  floatx4 acc[IC][4];
#pragma unroll
  for (int i = 0; i < IC; ++i)
#pragma unroll
    for (int j = 0; j < 4; ++j) acc[i][j] = (floatx4){0.f, 0.f, 0.f, 0.f};

  const int srow = l >> 2;                                  // staged quarter-row
  const int scb  = ((l & 3) ^ ((l >> 3) & 3)) * 16;         // swizzled global chunk (bytes)
  const int rm   = l & 15;                                  // fragment row within 16
  const int kcsw = ((l >> 4) ^ ((rm >> 1) & 3)) * 16;       // swizzled LDS chunk (bytes)

  for (int kt = 0; kt < K; kt += 64) {
#pragma unroll
    for (int h = 0; h < 2; ++h) {
#pragma unroll
      for (int i = 0; i < AST; ++i) {
        const int r = (i * 4 + w) * 16 + srow;
        gl2lds16((const char*)Ab + (size_t)(tile_m + r) * K * 2 + (kt + h * 32) * 2 + scb,
                 (char*)smA[h] + (i * 4 + w) * 1024);
      }
#pragma unroll
      for (int i = 0; i < 2; ++i) {
        const int r = (i * 4 + w) * 16 + srow;
        gl2lds16((const char*)Bb + (size_t)(tile_n + r) * K * 2 + (kt + h * 32) * 2 + scb,
                 (char*)smB[h] + (i * 4 + w) * 1024);
      }
    }
    __syncthreads();  // drains vmcnt -> both staged tiles visible

#pragma unroll
    for (int h = 0; h < 2; ++h) {
      short8 bfr[4];
#pragma unroll
      for (int j = 0; j < 4; ++j)
        bfr[j] = *(const short8*)((const char*)smB[h] + (wc * 64 + j * 16 + rm) * 64 + kcsw);
#pragma unroll
      for (int i = 0; i < IC; ++i) {
        const short8 af = *(const short8*)((const char*)smA[h] +
                                           (wr * (BM / 2) + i * 16 + rm) * 64 + kcsw);
#pragma unroll
        for (int j = 0; j < 4; ++j)
          acc[i][j] = __builtin_amdgcn_mfma_f32_16x16x32_bf16(af, bfr[j], acc[i][j], 0, 0, 0);
      }
    }
    __syncthreads();  // protect LDS before next stage
  }

#pragma unroll
  for (int i = 0; i < IC; ++i) {
#pragma unroll
    for (int j = 0; j < 4; ++j) {
      const int n = tile_n + wc * 64 + j * 16 + rm;
      const int m0 = tile_m + wr * (BM / 2) + i * 16 + (l >> 4) * 4;
      if (EPI == 0) {
        const float bv = bias[(size_t)z * sBias + n];
        unsigned short* C = (unsigned short*)Cv + (size_t)z * sC;
#pragma unroll
        for (int r = 0; r < 4; ++r)
          C[(size_t)(m0 + r) * N + n] = bf16_rne(acc[i][j][r] + bv);
      } else if (EPI == 1) {
        float* C = (float*)Cv + (size_t)z * sC;
#pragma unroll
        for (int r = 0; r < 4; ++r)
          C[(size_t)(m0 + r) * N + n] = acc[i][j][r] * scale;
      } else {
        unsigned short* C = (unsigned short*)Cv + (size_t)z * sC;
#pragma unroll
        for (int r = 0; r < 4; ++r)
          C[(size_t)(m0 + r) * N + n] = bf16_rne(acc[i][j][r] * scale);
      }
    }
  }
}

// ================= 8-phase 256x256 BT-GEMM (T2+T3+T4+T5), BK=64, 8 waves =================
// Faithful m201-template idiom this round:
//   loads -> s_barrier -> s_waitcnt lgkmcnt(0) -> sched_barrier(0) ->
//   setprio(1) -> 16 MFMA -> setprio(0) -> sched_barrier(0) -> s_barrier
// MFMA clusters are pinned by sched_barrier(0) at both edges (rule #18: memory
// clobbers do NOT order register-only MFMAs; the round-1 regression was the
// compiler smearing MFMAs across my barriers).
// Staging choreography (verified r0): iter t stages Ah1(t+1)->nxt (P1),
// Bh0+Bh1(t+2)->cur (P3, B-region reads done at P2 barrier), Ah0(t+2)->cur
// (P4, A-region reads done at P3 barrier). vmcnt(6) at P4 end == the 3 newest
// half-tiles (all tile t+2) stay in flight; tile t+1 guaranteed landed.
#define SCB0() __builtin_amdgcn_sched_barrier(0)

#define LOAD_A8(mh)                                                            \
  _Pragma("unroll") for (int f = 0; f < 4; ++f) {                              \
    const char* p_ = (const char*)sa + ((wr * 128 + (mh) * 64 + f * 16) * 128);\
    a[f][0] = *(const short8*)(p_ + aoff0);                                    \
    a[f][1] = *(const short8*)(p_ + aoff1);                                    \
  }

#define LOAD_B8(nh, barr)                                                      \
  _Pragma("unroll") for (int j = 0; j < 2; ++j) {                              \
    const char* p_ = (const char*)sb + ((wc * 64 + (nh) * 32 + j * 16) * 128); \
    barr[j][0] = *(const short8*)(p_ + aoff0);                                 \
    barr[j][1] = *(const short8*)(p_ + aoff1);                                 \
  }

#define QUAD8(mh, nh, barr)                                                    \
  _Pragma("unroll") for (int f = 0; f < 4; ++f)                                \
  _Pragma("unroll") for (int j = 0; j < 2; ++j)                                \
  _Pragma("unroll") for (int kk = 0; kk < 2; ++kk)                             \
    acc[(mh) * 4 + f][(nh) * 2 + j] =                                          \
        __builtin_amdgcn_mfma_f32_16x16x32_bf16(                               \
            a[f][kk], barr[j][kk], acc[(mh) * 4 + f][(nh) * 2 + j], 0, 0, 0);

#define MFMA_PHASE(mh, nh, barr)                                               \
  __builtin_amdgcn_s_barrier();                                                \
  asm volatile("s_waitcnt lgkmcnt(0)");                                        \
  SCB0();                                                                      \
  __builtin_amdgcn_s_setprio(1);                                               \
  QUAD8(mh, nh, barr)                                                          \
  __builtin_amdgcn_s_setprio(0);                                               \
  SCB0();                                                                      \
  __builtin_amdgcn_s_barrier();

#define STAGE8(mat, row0, kt, ldsb)                                            \
  _Pragma("unroll") for (int r = 0; r < 2; ++r)                                \
    gl2lds16((const char*)(mat) +                                              \
                 ((size_t)((row0) + r * 64 + stg_row) * K + (kt)) * 2 + stg_cb,\
             (char*)(ldsb) + r * 8192 + w * 1024);

#define STAGE8_A(buf, half, kt) \
  STAGE8(Ab, tile_m + (half) * 128, kt, (char*)smA[buf] + (half) * 16384)
#define STAGE8_B(buf, half, kt) \
  STAGE8(Bb, tile_n + (half) * 128, kt, (char*)smB[buf] + (half) * 16384)

template <int EPI>
__global__ __launch_bounds__(512, 2) void gemm8_bt(
    const unsigned short* __restrict__ A, const unsigned short* __restrict__ Bm,
    void* __restrict__ Cv, const float* __restrict__ bias,
    int N, int K, float scale,
    long long sA, long long sB, long long sC, long long sBias) {
  __shared__ unsigned short smA[2][256 * 64];
  __shared__ unsigned short smB[2][256 * 64];

  // XCD-aware remap (grid total = 256, divisible by 8)
  const int gx = gridDim.x, gy = gridDim.y;
  const int lin = blockIdx.x + gx * (blockIdx.y + gy * blockIdx.z);
  const int total = gx * gy * gridDim.z;
  const int g = (lin & 7) * (total >> 3) + (lin >> 3);
  const int z = g / (gx * gy);
  const int rem = g - z * (gx * gy);
  const int by = rem / gx;
  const int bx = rem - by * gx;

  const unsigned short* Ab = A + (size_t)z * sA;
  const unsigned short* Bb = Bm + (size_t)z * sB;
  const int tile_n = bx * 256;
  const int tile_m = by * 256;

  const int tid = threadIdx.x;
  const int w = tid >> 6, l = tid & 63;
  const int wr = w >> 2, wc = w & 3;      // 2x4 wave grid

  // staging constants: thread covers LDS row (r*64 + stg_row), chunk l&7
  const int stg_row = w * 8 + (l >> 3);               // 0..63 (+ r*64)
  const int stg_cb  = (((l & 7) ^ ((stg_row & 15) >> 1)) << 4);

  // fragment-read constants
  const int rm = l & 15, kc = l >> 4;
  const int q8 = (rm >> 1) & 7;
  const int aoff0 = rm * 128 + ((kc ^ q8) << 4);
  const int aoff1 = aoff0 ^ 64;                       // k-half 1 (chunk bit2)

  const int NT = K >> 6;

  floatx4 acc[8][4];
#pragma unroll
  for (int i = 0; i < 8; ++i)
#pragma unroll
    for (int j = 0; j < 4; ++j) acc[i][j] = (floatx4){0.f, 0.f, 0.f, 0.f};

  short8 a[4][2], b0[2][2], b1[2][2];

  // ---- prologue: tile0 (4 halves) + Bh0/Bh1/Ah0 of tile1; vmcnt(6) => tile0 landed
  {
    const int k1 = (NT > 1 ? 64 : 0);
    STAGE8_A(0, 0, 0);
    STAGE8_A(0, 1, 0);
    STAGE8_B(0, 0, 0);
    STAGE8_B(0, 1, 0);
    STAGE8_B(1, 0, k1);
    STAGE8_B(1, 1, k1);
    STAGE8_A(1, 0, k1);
  }
  asm volatile("s_waitcnt vmcnt(6)");
  __builtin_amdgcn_s_barrier();

  for (int tt = 0; tt < NT; ++tt) {
    const int cur = tt & 1, nxt = cur ^ 1;
    const unsigned short* sa = smA[cur];
    const unsigned short* sb = smB[cur];
    const int ktn  = ((tt + 1 < NT) ? tt + 1 : NT - 1) * 64;  // tile t+1 (clamped)
    const int ktn2 = ((tt + 2 < NT) ? tt + 2 : NT - 1) * 64;  // tile t+2 (clamped)

    // ---- P1: read A-mh0 + B-nh0; stage Ah1(t+1)->nxt
    LOAD_A8(0)
    LOAD_B8(0, b0)
    STAGE8_A(nxt, 1, ktn)
    MFMA_PHASE(0, 0, b0)

    // ---- P2: read B-nh1
    LOAD_B8(1, b1)
    MFMA_PHASE(0, 1, b1)

    // ---- P3: read A-mh1; stage Bh0+Bh1(t+2)->cur (B-region of cur dead)
    LOAD_A8(1)
    STAGE8_B(cur, 0, ktn2)
    STAGE8_B(cur, 1, ktn2)
    MFMA_PHASE(1, 1, b1)

    // ---- P4: no LDS reads (b0 live from P1); stage Ah0(t+2)->cur
    STAGE8_A(cur, 0, ktn2)
    __builtin_amdgcn_s_setprio(1);
    QUAD8(1, 0, b0)
    __builtin_amdgcn_s_setprio(0);
    SCB0();
    asm volatile("s_waitcnt vmcnt(6)");
    __builtin_amdgcn_s_barrier();
  }

  // Epilogue. C/D layout: col = lane&15, row = (lane>>4)*4 + reg.
  // jg INNER so one row's 4x32B pieces are 4 consecutive stores (full-line
  // writeback; round-1 jg-outer order cost 1.75x WRITE_SIZE amplification).
  float bvs[4] = {0.f, 0.f, 0.f, 0.f};
  if (EPI == 0) {
#pragma unroll
    for (int jg = 0; jg < 4; ++jg)
      bvs[jg] = bias[(size_t)z * sBias + tile_n + wc * 64 + jg * 16 + rm];
  }
#pragma unroll
  for (int fg = 0; fg < 8; ++fg) {
    const int m0 = tile_m + wr * 128 + fg * 16 + (l >> 4) * 4;
#pragma unroll
    for (int r = 0; r < 4; ++r) {
#pragma unroll
      for (int jg = 0; jg < 4; ++jg) {
        const int n = tile_n + wc * 64 + jg * 16 + rm;
        if (EPI == 0) {
          unsigned short* C = (unsigned short*)Cv + (size_t)z * sC;
          C[(size_t)(m0 + r) * N + n] = bf16_rne(acc[fg][jg][r] + bvs[jg]);
        } else if (EPI == 1) {
          float* C = (float*)Cv + (size_t)z * sC;
          C[(size_t)(m0 + r) * N + n] = acc[fg][jg][r] * scale;
        } else {
          unsigned short* C = (unsigned short*)Cv + (size_t)z * sC;
          C[(size_t)(m0 + r) * N + n] = bf16_rne(acc[fg][jg][r] * scale);
        }
      }
    }
  }
}

// ---------------- row softmax: bf16 logits [rows,2048] -> bf16 attn ----------------
__global__ __launch_bounds__(256) void softmax_bf16(
    const unsigned short* __restrict__ logits, unsigned short* __restrict__ attn) {
  const int row = blockIdx.x;
  const int t = threadIdx.x;
  uint4 raw = *(const uint4*)(logits + (size_t)row * S_ + t * 8);
  float x[8];
  const uint32_t ru[4] = {raw.x, raw.y, raw.z, raw.w};
#pragma unroll
  for (int i = 0; i < 4; ++i) {
    union { uint32_t u; float f; } lo, hi;
    lo.u = ru[i] << 16;
    hi.u = ru[i] & 0xffff0000u;
    x[2 * i] = lo.f;
    x[2 * i + 1] = hi.f;
  }
  float m = x[0];
#pragma unroll
  for (int i = 1; i < 8; ++i) m = fmaxf(m, x[i]);
#pragma unroll
  for (int off = 32; off > 0; off >>= 1) m = fmaxf(m, __shfl_xor(m, off));
  __shared__ float sm4[4], ss4[4];
  const int wv = t >> 6, ln = t & 63;
  if (ln == 0) sm4[wv] = m;
  __syncthreads();
  m = fmaxf(fmaxf(sm4[0], sm4[1]), fmaxf(sm4[2], sm4[3]));
  float s = 0.f;
  const float LOG2E = 1.44269504088896340736f;
#pragma unroll
  for (int i = 0; i < 8; ++i) {
    x[i] = exp2f((x[i] - m) * LOG2E);
    s += x[i];
  }
#pragma unroll
  for (int off = 32; off > 0; off >>= 1) s += __shfl_xor(s, off);
  if (ln == 0) ss4[wv] = s;
  __syncthreads();
  s = ss4[0] + ss4[1] + ss4[2] + ss4[3];
  const float inv = 1.0f / s;
  uint32_t p[4];
#pragma unroll
  for (int i = 0; i < 4; ++i)
    p[i] = (uint32_t)bf16_rne(x[2 * i] * inv) |
           ((uint32_t)bf16_rne(x[2 * i + 1] * inv) << 16);
  *(uint4*)(attn + (size_t)row * S_ + t * 8) = make_uint4(p[0], p[1], p[2], p[3]);
}

extern "C" void kernel_launch(void* const* d_in, const int* in_sizes, int n_in,
                              void* d_out, int out_size, void* d_ws, size_t ws_size,
                              hipStream_t stream) {
  (void)in_sizes; (void)n_in; (void)out_size; (void)ws_size;
  const float* query  = (const float*)d_in[0];
  const float* key_in = (const float*)d_in[1];
  const float* value  = (const float*)d_in[2];
  const float* Wq     = (const float*)d_in[3];
  const float* bq     = (const float*)d_in[4];
  const float* Wk     = (const float*)d_in[5];
  const float* bk     = (const float*)d_in[6];
  // d_in[7]=Wv, d_in[8]=bv: unused by the reference math (original model quirk).
  float* out = (float*)d_out;

  // Workspace layout (149 MiB used; every byte written before read each call)
  char* ws = (char*)d_ws;
  const size_t MiB = 1024 * 1024;
  unsigned short* Xq  = (unsigned short*)(ws);              // 16 MiB  query bf16
  unsigned short* Xk  = (unsigned short*)(ws + 16 * MiB);   // 16 MiB  key_in bf16 (contiguous after Xq)
  unsigned short* Wqb = (unsigned short*)(ws + 32 * MiB);   //  2 MiB  Wq bf16
  unsigned short* Wkb = (unsigned short*)(ws + 34 * MiB);   //  2 MiB  Wk bf16 (contiguous after Wqb)
  float*          Bias= (float*)(ws + 36 * MiB);            //  8 KiB  [bq | bk] packed
  unsigned short* Vt  = (unsigned short*)(ws + 37 * MiB);   // 16 MiB  value^T bf16 [B,D,S]
  unsigned short* Qp  = (unsigned short*)(ws + 53 * MiB);   // 16 MiB  Q bf16
  unsigned short* Kp  = (unsigned short*)(ws + 69 * MiB);   // 16 MiB  K bf16 (contiguous after Qp)
  unsigned short* Lg  = (unsigned short*)(ws + 85 * MiB);   // 32 MiB  logits bf16
  unsigned short* At  = (unsigned short*)(ws + 117 * MiB);  // 32 MiB  attn bf16

  // 1) all casts + bias pack + value transpose in one dispatch
  prep_all<<<26626, 256, 0, stream>>>(query, key_in, Wq, Wk, bq, bk, value,
                                      Xq, Xk, Wqb, Wkb, Bias, Vt);

  // 2) Q & K projections fused via z (8-phase 256^2: grid 4x32x2 = 256 = 1/CU)
  gemm8_bt<0><<<dim3(D_ / 256, B_ * S_ / 256, 2), 512, 0, stream>>>(
      Xq, Wqb, Qp, Bias, D_, D_, 0.f,
      (long long)B_ * S_ * D_, (long long)D_ * D_, (long long)B_ * S_ * D_, D_);

  // 3) logits = Q@K^T * D^-0.5 per batch -> bf16 (8-phase: grid 8x8x4 = 256)
  gemm8_bt<2><<<dim3(S_ / 256, S_ / 256, B_), 512, 0, stream>>>(
      Qp, Kp, Lg, nullptr, S_, D_, 0.03125f,
      (long long)S_ * D_, (long long)S_ * D_, (long long)S_ * S_, 0);

  // 4) attn = softmax(logits) rowwise -> bf16
  softmax_bf16<<<B_ * S_, 256, 0, stream>>>(Lg, At);

  // 5) out = attn @ value == BT-GEMM vs Vt (legacy BM=128: grid 8x16x4 = 512)
  gemm_bt<1, 128><<<dim3(D_ / 128, S_ / 128, B_), 256, 0, stream>>>(
      At, Vt, out, nullptr, D_, S_, 1.0f,
      (long long)S_ * S_, (long long)D_ * S_, (long long)S_ * D_, 0);
}

// Round 3
// 283.114 us; speedup vs baseline: 1.0713x; 1.0062x over previous
//
#include <hip/hip_runtime.h>
#include <hip/hip_bf16.h>
#include <stdint.h>

// Problem constants (reference: B=4, S=2048, D_IN=D_K=D_V=1024)
#define B_ 4
#define S_ 2048
#define D_ 1024

typedef __attribute__((ext_vector_type(8))) short short8;   // 8 bf16 = 4 VGPRs
typedef __attribute__((ext_vector_type(4))) float floatx4;  // MFMA C/D

__device__ __forceinline__ unsigned short bf16_rne(float f) {
  union { float f; uint32_t u; } c; c.f = f;
  uint32_t u = c.u;
  return (unsigned short)((u + 0x7fffu + ((u >> 16) & 1u)) >> 16);
}

__device__ __forceinline__ void gl2lds16(const void* g, void* l) {
  // async global->LDS, 16B per lane; LDS dest is wave-uniform base + lane*16
  __builtin_amdgcn_global_load_lds(
      (const __attribute__((address_space(1))) void*)g,
      (__attribute__((address_space(3))) void*)l, 16, 0, 0);
}

// ---- merged prep v2: casts (32B load / 16B store per lane), bias pack, and
// ---- V-transpose (64x64 tile, float4-coalesced loads, 128B-contiguous
// ---- ushort4 stores). Round-2 version ran 2.3 TB/s; store-width was the gap.
__global__ __launch_bounds__(256) void prep_all(
    const float* __restrict__ q, const float* __restrict__ k,
    const float* __restrict__ wq, const float* __restrict__ wk,
    const float* __restrict__ bq, const float* __restrict__ bk,
    const float* __restrict__ v,
    unsigned short* __restrict__ oq, unsigned short* __restrict__ ok,
    unsigned short* __restrict__ owq, unsigned short* __restrict__ owk,
    float* __restrict__ bias, unsigned short* __restrict__ vt) {
  // 17.4 KB static LDS: does not cap cast-block occupancy (thread limit of
  // 8 blocks/CU binds first at 256 threads/block).
  __shared__ float tile[64][68];   // [s][d], row = 272B = 17 x 16B (float4-aligned)
  const int blk = blockIdx.x;
  if (blk < 9216) {
    // ---- casts: each thread converts 8 f32 -> 8 bf16 (two float4 loads, one uint4 store)
    int i = blk * 256 + threadIdx.x;
    const float* src; unsigned short* dst; int off;
    if (i < 1048576)      { src = q;  dst = oq;  off = i; }
    else if (i < 2097152) { src = k;  dst = ok;  off = i - 1048576; }
    else if (i < 2228224) { src = wq; dst = owq; off = i - 2097152; }
    else                  { src = wk; dst = owk; off = i - 2228224; }
    float4 v0 = ((const float4*)src)[2 * off];
    float4 v1 = ((const float4*)src)[2 * off + 1];
    uint4 o;
    o.x = (uint32_t)bf16_rne(v0.x) | ((uint32_t)bf16_rne(v0.y) << 16);
    o.y = (uint32_t)bf16_rne(v0.z) | ((uint32_t)bf16_rne(v0.w) << 16);
    o.z = (uint32_t)bf16_rne(v1.x) | ((uint32_t)bf16_rne(v1.y) << 16);
    o.w = (uint32_t)bf16_rne(v1.z) | ((uint32_t)bf16_rne(v1.w) << 16);
    ((uint4*)dst)[off] = o;
  } else if (blk < 9218) {
    int j = (blk - 9216) * 256 + threadIdx.x;  // 0..511
    const float* src = (j < 256) ? bq : bk;
    ((float4*)bias)[j] = ((const float4*)src)[j & 255];
  } else {
    // ---- V transpose: 64(s) x 64(d) tile per block.
    const int bi = blk - 9218;              // 0..2047
    const int d0 = (bi & 15) * 64;          // D/64 = 16
    const int s0 = ((bi >> 4) & 31) * 64;   // S/64 = 32
    const int b  = bi >> 9;                 // B = 4
    const int u  = threadIdx.x;
    const float* src = v + (size_t)b * S_ * D_;
    const int dq = (u & 15) * 4, sr = u >> 4;   // load: 16 lanes x float4 = 256B/row
#pragma unroll
    for (int p = 0; p < 4; ++p)
      *(float4*)&tile[p * 16 + sr][dq] =
          *(const float4*)&src[(size_t)(s0 + p * 16 + sr) * D_ + d0 + dq];
    __syncthreads();
    unsigned short* dst = vt + (size_t)b * D_ * S_;
    const int sq = (u & 15) * 4, dr0 = u >> 4;  // store: 16 lanes x ushort4 = 128B/row
#pragma unroll
    for (int p = 0; p < 4; ++p) {
      const int dr = p * 16 + dr0;
      ushort4 o;
      o.x = bf16_rne(tile[sq + 0][dr]);
      o.y = bf16_rne(tile[sq + 1][dr]);
      o.z = bf16_rne(tile[sq + 2][dr]);
      o.w = bf16_rne(tile[sq + 3][dr]);
      *(ushort4*)&dst[(size_t)(d0 + dr) * S_ + s0 + sq] = o;
    }
  }
}

// ---------------- BT-GEMM: C[m,n] = sum_k A[m,k]*B[n,k], bf16 in, fp32 accum ---------------
// Block tile BM x 128, 4 waves (2x2), wave tile (BM/2) x 64. TWO BK=32 stages
// per barrier pair. XOR bank swizzle (zero conflicts). XCD-aware block remap.
// EPI 0: bf16 = acc + bias[n]; EPI 1: f32 = acc*scale; EPI 2: bf16 = acc*scale.
// (8-phase 256^2 port tried rounds 0-2: 46.5us vs this kernel's 44.6us on this
// shape despite full template pinning — reverted per pre-committed rule.)
template <int EPI, int BM>
__global__ __launch_bounds__(256, BM == 128 ? 3 : 2) void gemm_bt(
    const unsigned short* __restrict__ A, const unsigned short* __restrict__ Bm,
    void* __restrict__ Cv, const float* __restrict__ bias,
    int N, int K, float scale,
    long long sA, long long sB, long long sC, long long sBias) {
  constexpr int IC = BM / 32;    // A-frags per wave (m direction)
  constexpr int AST = BM / 64;   // A staging instrs per thread per k32
  __shared__ unsigned short smA[2][BM * 32];
  __shared__ unsigned short smB[2][128 * 32];

  const int gx = gridDim.x, gy = gridDim.y;
  const int lin = blockIdx.x + gx * (blockIdx.y + gy * blockIdx.z);
  const int total = gx * gy * gridDim.z;
  const int g = (lin & 7) * (total >> 3) + (lin >> 3);
  const int z = g / (gx * gy);
  const int rem = g - z * (gx * gy);
  const int by = rem / gx;
  const int bx = rem - by * gx;

  const unsigned short* Ab = A + (size_t)z * sA;
  const unsigned short* Bb = Bm + (size_t)z * sB;

  const int tile_n = bx * 128;
  const int tile_m = by * BM;

  const int t = threadIdx.x;
  const int w = t >> 6;        // wave 0..3
  const int l = t & 63;        // lane
  const int wr = w >> 1, wc = w & 1;  // 2x2 wave grid

  floatx4 acc[IC][4];
#pragma unroll
  for (int i = 0; i < IC; ++i)
#pragma unroll
    for (int j = 0; j < 4; ++j) acc[i][j] = (floatx4){0.f, 0.f, 0.f, 0.f};

  const int srow = l >> 2;                                  // staged quarter-row
  const int scb  = ((l & 3) ^ ((l >> 3) & 3)) * 16;         // swizzled global chunk (bytes)
  const int rm   = l & 15;                                  // fragment row within 16
  const int kcsw = ((l >> 4) ^ ((rm >> 1) & 3)) * 16;       // swizzled LDS chunk (bytes)

  for (int kt = 0; kt < K; kt += 64) {
#pragma unroll
    for (int h = 0; h < 2; ++h) {
#pragma unroll
      for (int i = 0; i < AST; ++i) {
        const int r = (i * 4 + w) * 16 + srow;
        gl2lds16((const char*)Ab + (size_t)(tile_m + r) * K * 2 + (kt + h * 32) * 2 + scb,
                 (char*)smA[h] + (i * 4 + w) * 1024);
      }
#pragma unroll
      for (int i = 0; i < 2; ++i) {
        const int r = (i * 4 + w) * 16 + srow;
        gl2lds16((const char*)Bb + (size_t)(tile_n + r) * K * 2 + (kt + h * 32) * 2 + scb,
                 (char*)smB[h] + (i * 4 + w) * 1024);
      }
    }
    __syncthreads();  // drains vmcnt -> both staged tiles visible

#pragma unroll
    for (int h = 0; h < 2; ++h) {
      short8 bfr[4];
#pragma unroll
      for (int j = 0; j < 4; ++j)
        bfr[j] = *(const short8*)((const char*)smB[h] + (wc * 64 + j * 16 + rm) * 64 + kcsw);
#pragma unroll
      for (int i = 0; i < IC; ++i) {
        const short8 af = *(const short8*)((const char*)smA[h] +
                                           (wr * (BM / 2) + i * 16 + rm) * 64 + kcsw);
#pragma unroll
        for (int j = 0; j < 4; ++j)
          acc[i][j] = __builtin_amdgcn_mfma_f32_16x16x32_bf16(af, bfr[j], acc[i][j], 0, 0, 0);
      }
    }
    __syncthreads();  // protect LDS before next stage
  }

  // Epilogue. C/D layout: col = lane&15, row = (lane>>4)*4 + reg  [m89/m91-verified]
#pragma unroll
  for (int i = 0; i < IC; ++i) {
#pragma unroll
    for (int j = 0; j < 4; ++j) {
      const int n = tile_n + wc * 64 + j * 16 + rm;
      const int m0 = tile_m + wr * (BM / 2) + i * 16 + (l >> 4) * 4;
      if (EPI == 0) {
        const float bv = bias[(size_t)z * sBias + n];
        unsigned short* C = (unsigned short*)Cv + (size_t)z * sC;
#pragma unroll
        for (int r = 0; r < 4; ++r)
          C[(size_t)(m0 + r) * N + n] = bf16_rne(acc[i][j][r] + bv);
      } else if (EPI == 1) {
        float* C = (float*)Cv + (size_t)z * sC;
#pragma unroll
        for (int r = 0; r < 4; ++r)
          C[(size_t)(m0 + r) * N + n] = acc[i][j][r] * scale;
      } else {
        unsigned short* C = (unsigned short*)Cv + (size_t)z * sC;
#pragma unroll
        for (int r = 0; r < 4; ++r)
          C[(size_t)(m0 + r) * N + n] = bf16_rne(acc[i][j][r] * scale);
      }
    }
  }
}

// ---------------- row softmax: bf16 logits [rows,2048] -> bf16 attn ----------------
__global__ __launch_bounds__(256) void softmax_bf16(
    const unsigned short* __restrict__ logits, unsigned short* __restrict__ attn) {
  const int row = blockIdx.x;
  const int t = threadIdx.x;
  uint4 raw = *(const uint4*)(logits + (size_t)row * S_ + t * 8);
  float x[8];
  const uint32_t ru[4] = {raw.x, raw.y, raw.z, raw.w};
#pragma unroll
  for (int i = 0; i < 4; ++i) {
    union { uint32_t u; float f; } lo, hi;
    lo.u = ru[i] << 16;
    hi.u = ru[i] & 0xffff0000u;
    x[2 * i] = lo.f;
    x[2 * i + 1] = hi.f;
  }
  float m = x[0];
#pragma unroll
  for (int i = 1; i < 8; ++i) m = fmaxf(m, x[i]);
#pragma unroll
  for (int off = 32; off > 0; off >>= 1) m = fmaxf(m, __shfl_xor(m, off));
  __shared__ float sm4[4], ss4[4];
  const int wv = t >> 6, ln = t & 63;
  if (ln == 0) sm4[wv] = m;
  __syncthreads();
  m = fmaxf(fmaxf(sm4[0], sm4[1]), fmaxf(sm4[2], sm4[3]));
  float s = 0.f;
  const float LOG2E = 1.44269504088896340736f;
#pragma unroll
  for (int i = 0; i < 8; ++i) {
    x[i] = exp2f((x[i] - m) * LOG2E);
    s += x[i];
  }
#pragma unroll
  for (int off = 32; off > 0; off >>= 1) s += __shfl_xor(s, off);
  if (ln == 0) ss4[wv] = s;
  __syncthreads();
  s = ss4[0] + ss4[1] + ss4[2] + ss4[3];
  const float inv = 1.0f / s;
  uint32_t p[4];
#pragma unroll
  for (int i = 0; i < 4; ++i)
    p[i] = (uint32_t)bf16_rne(x[2 * i] * inv) |
           ((uint32_t)bf16_rne(x[2 * i + 1] * inv) << 16);
  *(uint4*)(attn + (size_t)row * S_ + t * 8) = make_uint4(p[0], p[1], p[2], p[3]);
}

extern "C" void kernel_launch(void* const* d_in, const int* in_sizes, int n_in,
                              void* d_out, int out_size, void* d_ws, size_t ws_size,
                              hipStream_t stream) {
  (void)in_sizes; (void)n_in; (void)out_size; (void)ws_size;
  const float* query  = (const float*)d_in[0];
  const float* key_in = (const float*)d_in[1];
  const float* value  = (const float*)d_in[2];
  const float* Wq     = (const float*)d_in[3];
  const float* bq     = (const float*)d_in[4];
  const float* Wk     = (const float*)d_in[5];
  const float* bk     = (const float*)d_in[6];
  // d_in[7]=Wv, d_in[8]=bv: unused by the reference math (original model quirk).
  float* out = (float*)d_out;

  // Workspace layout (149 MiB used; every byte written before read each call)
  char* ws = (char*)d_ws;
  const size_t MiB = 1024 * 1024;
  unsigned short* Xq  = (unsigned short*)(ws);              // 16 MiB  query bf16
  unsigned short* Xk  = (unsigned short*)(ws + 16 * MiB);   // 16 MiB  key_in bf16 (contiguous after Xq)
  unsigned short* Wqb = (unsigned short*)(ws + 32 * MiB);   //  2 MiB  Wq bf16
  unsigned short* Wkb = (unsigned short*)(ws + 34 * MiB);   //  2 MiB  Wk bf16 (contiguous after Wqb)
  float*          Bias= (float*)(ws + 36 * MiB);            //  8 KiB  [bq | bk] packed
  unsigned short* Vt  = (unsigned short*)(ws + 37 * MiB);   // 16 MiB  value^T bf16 [B,D,S]
  unsigned short* Qp  = (unsigned short*)(ws + 53 * MiB);   // 16 MiB  Q bf16
  unsigned short* Kp  = (unsigned short*)(ws + 69 * MiB);   // 16 MiB  K bf16 (contiguous after Qp)
  unsigned short* Lg  = (unsigned short*)(ws + 85 * MiB);   // 32 MiB  logits bf16
  unsigned short* At  = (unsigned short*)(ws + 117 * MiB);  // 32 MiB  attn bf16

  // 1) all casts + bias pack + value transpose in one dispatch
  prep_all<<<11266, 256, 0, stream>>>(query, key_in, Wq, Wk, bq, bk, value,
                                      Xq, Xk, Wqb, Wkb, Bias, Vt);

  // 2) Q & K projections fused via z (BM=256: grid 8x32x2 = 512)
  gemm_bt<0, 256><<<dim3(D_ / 128, B_ * S_ / 256, 2), 256, 0, stream>>>(
      Xq, Wqb, Qp, Bias, D_, D_, 0.f,
      (long long)B_ * S_ * D_, (long long)D_ * D_, (long long)B_ * S_ * D_, D_);

  // 3) logits = Q@K^T * D^-0.5 per batch -> bf16 (BM=256: grid 16x8x4 = 512)
  gemm_bt<2, 256><<<dim3(S_ / 128, S_ / 256, B_), 256, 0, stream>>>(
      Qp, Kp, Lg, nullptr, S_, D_, 0.03125f,
      (long long)S_ * D_, (long long)S_ * D_, (long long)S_ * S_, 0);

  // 4) attn = softmax(logits) rowwise -> bf16
  softmax_bf16<<<B_ * S_, 256, 0, stream>>>(Lg, At);

  // 5) out = attn @ value == BT-GEMM vs Vt (BM=128: grid 8x16x4 = 512)
  gemm_bt<1, 128><<<dim3(D_ / 128, S_ / 128, B_), 256, 0, stream>>>(
      At, Vt, out, nullptr, D_, S_, 1.0f,
      (long long)S_ * S_, (long long)D_ * S_, (long long)S_ * D_, 0);
}